// Round 1
// baseline (3147.920 us; speedup 1.0000x reference)
//
#include <hip/hip_runtime.h>

#define T_ 4096
#define H_ 2048
#define E_ 64
#define F_ 768
#define K_ 8
#define C_ 1024

typedef unsigned short u16;
typedef __attribute__((ext_vector_type(8))) short bf16x8;   // 8 bf16 (4 VGPRs), per guide §3
typedef __attribute__((ext_vector_type(4))) float f32x4;

__device__ __forceinline__ u16 f2b(float f) {
  unsigned u = __builtin_bit_cast(unsigned, f);
  u += 0x7fffu + ((u >> 16) & 1u);   // RNE
  return (u16)(u >> 16);
}

// ---------------- x -> bf16 ----------------
__global__ __launch_bounds__(256) void cvt_x_kernel(const float* __restrict__ x, u16* __restrict__ xb) {
  int i = blockIdx.x * 256 + threadIdx.x;
  float4 v = ((const float4*)x)[i];
  ushort4 o;
  o.x = f2b(v.x); o.y = f2b(v.y); o.z = f2b(v.z); o.w = f2b(v.w);
  ((ushort4*)xb)[i] = o;
}

// ---------------- router: fp32 logits, top-8, renormalized softmax weights ----------------
__global__ __launch_bounds__(256) void router_kernel(const float* __restrict__ x, const float* __restrict__ gw,
                                                     int* __restrict__ topi, float* __restrict__ topw) {
  __shared__ float xs[4][H_];
  __shared__ float lg[4][E_];
  int t0 = blockIdx.x * 4;
  const float4* xsrc = (const float4*)(x + (size_t)t0 * H_);
  float4* xdst = (float4*)&xs[0][0];
#pragma unroll
  for (int j = 0; j < 8; ++j) xdst[j * 256 + threadIdx.x] = xsrc[j * 256 + threadIdx.x];
  __syncthreads();
  int e  = threadIdx.x & 63;
  int tt = threadIdx.x >> 6;
  const float4* g4 = (const float4*)(gw + (size_t)e * H_);
  const float4* x4 = (const float4*)&xs[tt][0];
  float a0 = 0.f, a1 = 0.f, a2 = 0.f, a3 = 0.f;
  for (int i = 0; i < H_ / 4; ++i) {
    float4 g = g4[i]; float4 xv = x4[i];
    a0 += g.x * xv.x; a1 += g.y * xv.y; a2 += g.z * xv.z; a3 += g.w * xv.w;
  }
  lg[tt][e] = (a0 + a1) + (a2 + a3);
  __syncthreads();
  int wave = threadIdx.x >> 6;
  int lane = threadIdx.x & 63;
  int t = t0 + wave;
  float v = lg[wave][lane];
  float m = 0.f, s = 0.f, myw = 0.f;
  int myi = 0;
#pragma unroll
  for (int k = 0; k < 8; ++k) {
    float bv = v; int bi = lane;
#pragma unroll
    for (int off = 32; off > 0; off >>= 1) {
      float ov = __shfl_down(bv, off);
      int   oi = __shfl_down(bi, off);
      if (ov > bv || (ov == bv && oi < bi)) { bv = ov; bi = oi; }
    }
    bv = __shfl(bv, 0); bi = __shfl(bi, 0);
    if (k == 0) m = bv;
    float ev = expf(bv - m);
    s += ev;
    if (lane == k) { myi = bi; myw = ev; }
    if (lane == bi) v = -__builtin_inff();
  }
  if (lane < 8) {
    topi[t * K_ + lane] = myi;
    topw[t * K_ + lane] = myw / s;
  }
}

// ---------------- dispatch: slot assignment (order-free: no expert can overflow C=2x mean) ----------------
__global__ __launch_bounds__(256) void dispatch_kernel(const int* __restrict__ topi, int* __restrict__ counts,
                                                       int* __restrict__ posv, int* __restrict__ perm) {
  int i = blockIdx.x * 256 + threadIdx.x;
  int e = topi[i];
  int p = atomicAdd(&counts[e], 1);
  posv[i] = p;
  if (p < C_) perm[e * C_ + p] = i >> 3;   // token index
}

// ---------------- GEMM1: act[rows,768] = silu(Xg)*Xu, gathered A, fused SwiGLU ----------------
// block: 128 rows x 64 act-cols (gu cols {c..c+64} U {768+c..768+c+64}), 256 threads, 4 waves of 32x128
__global__ __launch_bounds__(256, 2) void gemm1_kernel(const u16* __restrict__ xb, const float* __restrict__ wgu,
                                                       const int* __restrict__ perm, const int* __restrict__ counts,
                                                       u16* __restrict__ act) {
  int e  = blockIdx.z;
  int rb = blockIdx.y;
  int nb = blockIdx.x;   // 0..11
  int count = counts[e]; if (count > C_) count = C_;
  if (rb * 128 >= count) return;
  __shared__ __align__(16) u16 As[128][72];
  __shared__ __align__(16) u16 Bs[128][72];
  int tid = threadIdx.x;
  int arow = tid >> 1;
  int r = rb * 128 + arow;
  int tok = (r < count) ? perm[e * C_ + r] : -1;
  const u16* aptr = xb + ((tok >= 0) ? ((size_t)tok * H_) : 0) + (tid & 1) * 32;
  const float* wbase = wgu + (size_t)e * (H_ * 2 * F_);
  int lane = tid & 63, wave = tid >> 6;
  int fl = lane & 15, quad = lane >> 4;
  int m0 = wave * 32;
  f32x4 acc[2][8];
#pragma unroll
  for (int a = 0; a < 2; ++a)
#pragma unroll
    for (int b = 0; b < 8; ++b) acc[a][b] = (f32x4){0.f, 0.f, 0.f, 0.f};

  for (int kt = 0; kt < H_ / 64; ++kt) {
    int k0 = kt * 64;
    uint4 av[4];
    if (tok >= 0) {
      const uint4* ap = (const uint4*)(aptr + k0);
#pragma unroll
      for (int j = 0; j < 4; ++j) av[j] = ap[j];
    } else {
#pragma unroll
      for (int j = 0; j < 4; ++j) av[j] = (uint4){0u, 0u, 0u, 0u};
    }
    const float* wt = wbase + (size_t)k0 * (2 * F_);
    float4 r0[2], r1[2], r2[2], r3[2];
    int kk[2];
#pragma unroll
    for (int j = 0; j < 2; ++j) {
      int li = j * 256 + tid;
      int k4 = li >> 5;
      int n4 = li & 31;
      kk[j] = k4 * 4;
      int c = n4 * 4;
      int gcol = (c < 64) ? (nb * 64 + c) : (F_ + nb * 64 + (c - 64));
      const float* p = wt + (size_t)kk[j] * (2 * F_) + gcol;
      r0[j] = *(const float4*)(p);
      r1[j] = *(const float4*)(p + 2 * F_);
      r2[j] = *(const float4*)(p + 4 * F_);
      r3[j] = *(const float4*)(p + 6 * F_);
    }
    __syncthreads();   // previous iter's MFMA reads done
#pragma unroll
    for (int j = 0; j < 4; ++j) *(uint4*)&As[arow][(tid & 1) * 32 + j * 8] = av[j];
#pragma unroll
    for (int j = 0; j < 2; ++j) {
      ushort4 wv[4];
      wv[0] = (ushort4){f2b(r0[j].x), f2b(r1[j].x), f2b(r2[j].x), f2b(r3[j].x)};
      wv[1] = (ushort4){f2b(r0[j].y), f2b(r1[j].y), f2b(r2[j].y), f2b(r3[j].y)};
      wv[2] = (ushort4){f2b(r0[j].z), f2b(r1[j].z), f2b(r2[j].z), f2b(r3[j].z)};
      wv[3] = (ushort4){f2b(r0[j].w), f2b(r1[j].w), f2b(r2[j].w), f2b(r3[j].w)};
      int n4 = (j * 256 + tid) & 31;
      int c = n4 * 4;
#pragma unroll
      for (int i2 = 0; i2 < 4; ++i2) {
        int ni = (i2 + n4) & 3;   // rotate rows to spread LDS banks
        *(ushort4*)&Bs[c + ni][kk[j]] = wv[ni];
      }
    }
    __syncthreads();
#pragma unroll
    for (int kb = 0; kb < 2; ++kb) {
      int ko = kb * 32 + quad * 8;
      bf16x8 a0 = *(const bf16x8*)&As[m0 + fl][ko];
      bf16x8 a1 = *(const bf16x8*)&As[m0 + 16 + fl][ko];
#pragma unroll
      for (int nf = 0; nf < 8; ++nf) {
        bf16x8 bfr = *(const bf16x8*)&Bs[nf * 16 + fl][ko];
        acc[0][nf] = __builtin_amdgcn_mfma_f32_16x16x32_bf16(a0, bfr, acc[0][nf], 0, 0, 0);
        acc[1][nf] = __builtin_amdgcn_mfma_f32_16x16x32_bf16(a1, bfr, acc[1][nf], 0, 0, 0);
      }
    }
  }
  size_t rowbase = (size_t)e * C_;
#pragma unroll
  for (int mf = 0; mf < 2; ++mf)
#pragma unroll
    for (int nf = 0; nf < 4; ++nf)
#pragma unroll
      for (int rg = 0; rg < 4; ++rg) {
        float g = acc[mf][nf][rg];
        float u = acc[mf][nf + 4][rg];
        float a = (g / (1.f + __expf(-g))) * u;   // SiLU(g)*u
        int row = rb * 128 + m0 + mf * 16 + quad * 4 + rg;
        int col = nb * 64 + nf * 16 + fl;
        act[(rowbase + row) * F_ + col] = f2b(a);
      }
}

// ---------------- GEMM2: ye[rows,2048] = act @ w_down[e] ----------------
__global__ __launch_bounds__(256, 2) void gemm2_kernel(const u16* __restrict__ act, const float* __restrict__ wd,
                                                       const int* __restrict__ counts, u16* __restrict__ ye) {
  int e  = blockIdx.z;
  int rb = blockIdx.y;
  int nb = blockIdx.x;   // 0..15
  int count = counts[e]; if (count > C_) count = C_;
  if (rb * 128 >= count) return;
  __shared__ __align__(16) u16 As[128][72];
  __shared__ __align__(16) u16 Bs[128][72];
  int tid = threadIdx.x;
  int arow = tid >> 1;
  const u16* aptr = act + ((size_t)e * C_ + rb * 128 + arow) * F_ + (tid & 1) * 32;
  const float* wbase = wd + (size_t)e * (F_ * H_);
  int lane = tid & 63, wave = tid >> 6;
  int fl = lane & 15, quad = lane >> 4;
  int m0 = wave * 32;
  f32x4 acc[2][8];
#pragma unroll
  for (int a = 0; a < 2; ++a)
#pragma unroll
    for (int b = 0; b < 8; ++b) acc[a][b] = (f32x4){0.f, 0.f, 0.f, 0.f};

  for (int kt = 0; kt < F_ / 64; ++kt) {
    int k0 = kt * 64;
    uint4 av[4];
    const uint4* ap = (const uint4*)(aptr + k0);
#pragma unroll
    for (int j = 0; j < 4; ++j) av[j] = ap[j];
    const float* wt = wbase + (size_t)k0 * H_;
    float4 r0[2], r1[2], r2[2], r3[2];
    int kk[2];
#pragma unroll
    for (int j = 0; j < 2; ++j) {
      int li = j * 256 + tid;
      int k4 = li >> 5;
      int n4 = li & 31;
      kk[j] = k4 * 4;
      int gcol = nb * 128 + n4 * 4;
      const float* p = wt + (size_t)kk[j] * H_ + gcol;
      r0[j] = *(const float4*)(p);
      r1[j] = *(const float4*)(p + H_);
      r2[j] = *(const float4*)(p + 2 * H_);
      r3[j] = *(const float4*)(p + 3 * H_);
    }
    __syncthreads();
#pragma unroll
    for (int j = 0; j < 4; ++j) *(uint4*)&As[arow][(tid & 1) * 32 + j * 8] = av[j];
#pragma unroll
    for (int j = 0; j < 2; ++j) {
      ushort4 wv[4];
      wv[0] = (ushort4){f2b(r0[j].x), f2b(r1[j].x), f2b(r2[j].x), f2b(r3[j].x)};
      wv[1] = (ushort4){f2b(r0[j].y), f2b(r1[j].y), f2b(r2[j].y), f2b(r3[j].y)};
      wv[2] = (ushort4){f2b(r0[j].z), f2b(r1[j].z), f2b(r2[j].z), f2b(r3[j].z)};
      wv[3] = (ushort4){f2b(r0[j].w), f2b(r1[j].w), f2b(r2[j].w), f2b(r3[j].w)};
      int n4 = (j * 256 + tid) & 31;
      int c = n4 * 4;
#pragma unroll
      for (int i2 = 0; i2 < 4; ++i2) {
        int ni = (i2 + n4) & 3;
        *(ushort4*)&Bs[c + ni][kk[j]] = wv[ni];
      }
    }
    __syncthreads();
#pragma unroll
    for (int kb = 0; kb < 2; ++kb) {
      int ko = kb * 32 + quad * 8;
      bf16x8 a0 = *(const bf16x8*)&As[m0 + fl][ko];
      bf16x8 a1 = *(const bf16x8*)&As[m0 + 16 + fl][ko];
#pragma unroll
      for (int nf = 0; nf < 8; ++nf) {
        bf16x8 bfr = *(const bf16x8*)&Bs[nf * 16 + fl][ko];
        acc[0][nf] = __builtin_amdgcn_mfma_f32_16x16x32_bf16(a0, bfr, acc[0][nf], 0, 0, 0);
        acc[1][nf] = __builtin_amdgcn_mfma_f32_16x16x32_bf16(a1, bfr, acc[1][nf], 0, 0, 0);
      }
    }
  }
  size_t rowbase = (size_t)e * C_;
#pragma unroll
  for (int mf = 0; mf < 2; ++mf)
#pragma unroll
    for (int nf = 0; nf < 8; ++nf)
#pragma unroll
      for (int rg = 0; rg < 4; ++rg) {
        int row = rb * 128 + m0 + mf * 16 + quad * 4 + rg;
        int col = nb * 128 + nf * 16 + fl;
        ye[(rowbase + row) * H_ + col] = f2b(acc[mf][nf][rg]);
      }
}

// ---------------- combine: out[t] = sum_k w_k * ye[e_k, slot_k] ----------------
__global__ __launch_bounds__(256) void combine_kernel(const u16* __restrict__ ye, const int* __restrict__ topi,
                                                      const int* __restrict__ posv, const float* __restrict__ topw,
                                                      float* __restrict__ out) {
  int t = blockIdx.x, tid = threadIdx.x;
  __shared__ int se[8]; __shared__ int sp[8]; __shared__ float sw[8];
  if (tid < 8) { se[tid] = topi[t * 8 + tid]; sp[tid] = posv[t * 8 + tid]; sw[tid] = topw[t * 8 + tid]; }
  __syncthreads();
  int col = tid * 8;
  float acc[8];
#pragma unroll
  for (int j = 0; j < 8; ++j) acc[j] = 0.f;
#pragma unroll
  for (int k = 0; k < 8; ++k) {
    int p = sp[k];
    if (p >= C_) continue;
    uint4 v = *(const uint4*)(ye + ((size_t)se[k] * C_ + p) * H_ + col);
    float w = sw[k];
    unsigned arr[4] = {v.x, v.y, v.z, v.w};
#pragma unroll
    for (int j = 0; j < 4; ++j) {
      acc[2 * j]     += w * __builtin_bit_cast(float, arr[j] << 16);
      acc[2 * j + 1] += w * __builtin_bit_cast(float, arr[j] & 0xffff0000u);
    }
  }
  float4 o0 = {acc[0], acc[1], acc[2], acc[3]};
  float4 o1 = {acc[4], acc[5], acc[6], acc[7]};
  float* op = out + (size_t)t * H_ + col;
  *(float4*)op = o0;
  *(float4*)(op + 4) = o1;
}

extern "C" void kernel_launch(void* const* d_in, const int* in_sizes, int n_in,
                              void* d_out, int out_size, void* d_ws, size_t ws_size,
                              hipStream_t stream) {
  const float* x   = (const float*)d_in[0];
  const float* gw  = (const float*)d_in[1];
  const float* wgu = (const float*)d_in[2];
  const float* wd  = (const float*)d_in[3];
  float* out = (float*)d_out;

  char* w = (char*)d_ws;
  u16*  xb     = (u16*)(w + 0);              // 16,777,216 B
  int*  topi   = (int*)(w + 16777216);       //    131,072
  float* topw  = (float*)(w + 16908288);     //    131,072
  int*  posv   = (int*)(w + 17039360);       //    131,072
  int*  counts = (int*)(w + 17170432);       //        256
  int*  perm   = (int*)(w + 17170688);       //    262,144
  u16*  act    = (u16*)(w + 17432832);       // 100,663,296  [E*C, F] bf16
  u16*  ye     = (u16*)(w + 118096128);      // 268,435,456  [E*C, H] bf16  (total ~386.5 MB)

  hipMemsetAsync(counts, 0, 64 * sizeof(int), stream);
  cvt_x_kernel<<<(T_ * H_ / 4) / 256, 256, 0, stream>>>(x, xb);
  router_kernel<<<T_ / 4, 256, 0, stream>>>(x, gw, topi, topw);
  dispatch_kernel<<<(T_ * K_) / 256, 256, 0, stream>>>(topi, counts, posv, perm);
  gemm1_kernel<<<dim3(12, 8, E_), 256, 0, stream>>>(xb, wgu, perm, counts, act);
  gemm2_kernel<<<dim3(16, 8, E_), 256, 0, stream>>>(act, wd, counts, ye);
  combine_kernel<<<T_, 256, 0, stream>>>(ye, topi, posv, topw, out);
}